// Round 2
// baseline (1489.645 us; speedup 1.0000x reference)
//
#include <hip/hip_runtime.h>
#include <hip/hip_bf16.h>

#define BATCH   16
#define N_ANC   8649      // 31*31*9
#define SORT_N  16384     // padded pow2
#define PRE     6000
#define POST    1500
#define ROWW    188       // u32 words per mask row (6016 bits)
#define MROWS   6016      // 6000 rows + pad for prefetch overrun
#define PFD     16        // scan prefetch depth

// ---------------- Kernel 1: decode boxes + build sort keys ----------------
__global__ __launch_bounds__(256) void k_decode(
    const float* __restrict__ deltas, const float* __restrict__ probs,
    const float* __restrict__ anchors, float4* __restrict__ boxes,
    unsigned long long* __restrict__ keys)
{
    int t = blockIdx.x * 256 + threadIdx.x;
    if (t >= BATCH * SORT_N) return;
    int b = t / SORT_N;
    int n = t - b * SORT_N;
    if (n >= N_ANC) { keys[t] = ~0ULL; return; }

    float s = probs[(size_t)b * N_ANC + n];
    unsigned int bits = __float_as_uint(s);
    unsigned int u = bits ^ ((bits & 0x80000000u) ? 0xFFFFFFFFu : 0x80000000u);
    keys[(size_t)b * SORT_N + n] = ((unsigned long long)(~u) << 32) | (unsigned int)n;

    float4 a = ((const float4*)anchors)[n];
    float4 d = ((const float4*)deltas)[(size_t)b * N_ANC + n];
    float dy = d.x * 0.1f, dx = d.y * 0.1f, dh = d.z * 0.2f, dw = d.w * 0.2f;
    float ah = a.z - a.x, aw = a.w - a.y;
    float cy = a.x + 0.5f * ah, cx = a.y + 0.5f * aw;
    float bh = expf(dh) * ah, bw = expf(dw) * aw;
    float bcy = dy * ah + cy, bcx = dx * aw + cx;
    float y1 = bcy - 0.5f * bh, x1 = bcx - 0.5f * bw;
    boxes[(size_t)b * N_ANC + n] = make_float4(y1, x1, y1 + bh, x1 + bw);
}

// ---------------- Kernel 2: per-batch bitonic sort of 16384 keys ----------------
__global__ __launch_bounds__(1024) void k_sort(unsigned long long* __restrict__ keys)
{
    __shared__ unsigned long long sb[8192];   // 64 KB
    int b = blockIdx.x;
    unsigned long long* kb = keys + (size_t)b * SORT_N;

    // phase 1: sort each 8192-chunk (c0 asc, c1 desc via global-index direction)
    for (int c = 0; c < 2; c++) {
        unsigned long long* g = kb + c * 8192;
        for (int t = threadIdx.x; t < 8192; t += 1024) sb[t] = g[t];
        __syncthreads();
        for (int k = 2; k <= 8192; k <<= 1) {
            for (int j = k >> 1; j >= 1; j >>= 1) {
                for (int p = threadIdx.x; p < 4096; p += 1024) {
                    int i  = ((p & ~(j - 1)) << 1) | (p & (j - 1));
                    int gi = (c << 13) | i;
                    bool asc = ((gi & k) == 0);
                    unsigned long long a = sb[i], b2 = sb[i | j];
                    bool sw = asc ? (a > b2) : (a < b2);
                    if (sw) { sb[i] = b2; sb[i | j] = a; }
                }
                __syncthreads();
            }
        }
        for (int t = threadIdx.x; t < 8192; t += 1024) g[t] = sb[t];
        __syncthreads();
    }

    // phase 2: global j=8192 pass (all ascending)
    for (int p = threadIdx.x; p < 8192; p += 1024) {
        unsigned long long a = kb[p], b2 = kb[p + 8192];
        if (a > b2) { kb[p] = b2; kb[p + 8192] = a; }
    }
    __syncthreads();

    // finish merge of chunk 0 (holds global top-8192) in LDS
    for (int t = threadIdx.x; t < 8192; t += 1024) sb[t] = kb[t];
    __syncthreads();
    for (int j = 4096; j >= 1; j >>= 1) {
        for (int p = threadIdx.x; p < 4096; p += 1024) {
            int i = ((p & ~(j - 1)) << 1) | (p & (j - 1));
            unsigned long long a = sb[i], b2 = sb[i | j];
            if (a > b2) { sb[i] = b2; sb[i | j] = a; }
        }
        __syncthreads();
    }
    for (int t = threadIdx.x; t < 6016; t += 1024) kb[t] = sb[t];
}

// ---------------- Kernel 3: gather sorted boxes/scores ----------------
__global__ __launch_bounds__(256) void k_gather(
    const unsigned long long* __restrict__ keys, const float4* __restrict__ boxes,
    const float* __restrict__ probs,
    float4* __restrict__ sboxes, float* __restrict__ sscores)
{
    int t = blockIdx.x * 256 + threadIdx.x;
    if (t >= BATCH * PRE) return;
    int b = t / PRE;
    int r = t - b * PRE;
    unsigned long long k = keys[(size_t)b * SORT_N + r];
    int idx = (int)(k & 0xFFFFFFFFu);
    sboxes[(size_t)b * PRE + r]  = boxes[(size_t)b * N_ANC + idx];
    sscores[(size_t)b * PRE + r] = probs[(size_t)b * N_ANC + idx];
}

// ---------------- Kernel 4: IoU suppression bit-matrix (upper triangle) ----------------
__global__ __launch_bounds__(256) void k_iou(
    const float4* __restrict__ sboxes, unsigned int* __restrict__ mask)
{
    int b = blockIdx.y;
    int i = blockIdx.x * 256 + threadIdx.x;
    __shared__ float4 jb[128];

    float4 bi = make_float4(0, 0, 0, 0);
    float areai = 0.f;
    bool act = (i < PRE);
    if (act) {
        bi = sboxes[(size_t)b * PRE + i];
        areai = (bi.z - bi.x) * (bi.w - bi.y);
    }
    unsigned int* row = mask + ((size_t)b * MROWS + (size_t)(act ? i : 0)) * ROWW;

    for (int c = 0; c < 47; c++) {
        int j0 = c * 128;
        __syncthreads();
        if (threadIdx.x < 128) {
            int j = j0 + threadIdx.x;
            jb[threadIdx.x] = (j < PRE) ? sboxes[(size_t)b * PRE + j]
                                        : make_float4(0, 0, 0, 0);
        }
        __syncthreads();
        if (act) {
            #pragma unroll
            for (int wq = 0; wq < 4; wq++) {
                int jbase = j0 + wq * 32;
                unsigned int bitsw = 0u;
                if (jbase + 31 > i && jbase < PRE) {
                    for (int jj = 0; jj < 32; jj++) {
                        int j = jbase + jj;
                        if (j > i && j < PRE) {
                            float4 bj = jb[wq * 32 + jj];
                            float ih = fmaxf(fminf(bi.z, bj.z) - fmaxf(bi.x, bj.x), 0.0f);
                            float iw = fmaxf(fminf(bi.w, bj.w) - fmaxf(bi.y, bj.y), 0.0f);
                            float inter = ih * iw;
                            float areaj = (bj.z - bj.x) * (bj.w - bj.y);
                            float iou = inter / (areai + areaj - inter + 1e-8f);
                            if (iou > 0.7f) bitsw |= (1u << jj);
                        }
                    }
                }
                row[c * 4 + wq] = bitsw;
            }
        }
    }
}

// ---------------- Kernel 5: sequential suppression scan (1 wave / batch) ----------------
__global__ __launch_bounds__(64) void k_scan(
    const unsigned int* __restrict__ mask, int* __restrict__ out_idx,
    int* __restrict__ out_cnt)
{
    int b = blockIdx.x;
    int lane = threadIdx.x;
    const unsigned int* mb = mask + (size_t)b * MROWS * ROWW;

    unsigned int s0 = 0, s1 = 0, s2 = 0;      // words lane, lane+64, lane+128
    unsigned int p0[PFD], p1[PFD], p2[PFD];   // prefetch ring
    #pragma unroll
    for (int d = 0; d < PFD; d++) {
        const unsigned int* r = mb + (size_t)d * ROWW;
        p0[d] = r[lane];
        p1[d] = r[lane + 64];
        p2[d] = (lane < 60) ? r[lane + 128] : 0u;
    }

    int cnt = 0;
    int* oi = out_idx + b * POST;
    for (int base = 0; base < PRE; base += PFD) {
        #pragma unroll
        for (int d = 0; d < PFD; d++) {
            int i = base + d;
            int w = i >> 5;
            int slot = w >> 6;
            int src = w & 63;
            unsigned int val = (slot == 0) ? s0 : ((slot == 1) ? s1 : s2);
            unsigned int word = __shfl(val, src);
            bool sup = (word >> (i & 31)) & 1u;
            bool kept = (!sup) && (cnt < POST);
            if (kept) {
                if (lane == 0) oi[cnt] = i;
                cnt++;
                s0 |= p0[d]; s1 |= p1[d]; s2 |= p2[d];
            }
            const unsigned int* r = mb + (size_t)(i + PFD) * ROWW;
            p0[d] = r[lane];
            p1[d] = r[lane + 64];
            p2[d] = (lane < 60) ? r[lane + 128] : 0u;
        }
        if (cnt >= POST) break;
    }
    if (lane == 0) out_cnt[b] = cnt;
}

// ---------------- Kernel 6: compact + clip output ----------------
__global__ __launch_bounds__(256) void k_out(
    const float4* __restrict__ sboxes, const float* __restrict__ sscores,
    const int* __restrict__ out_idx, const int* __restrict__ out_cnt,
    float* __restrict__ out)
{
    int t = blockIdx.x * 256 + threadIdx.x;
    if (t >= BATCH * POST) return;
    int b = t / POST;
    int r = t - b * POST;
    float4 v = make_float4(0, 0, 0, 0);
    float sc = 0.f;
    if (r < out_cnt[b]) {
        int i = out_idx[b * POST + r];
        float4 bx = sboxes[(size_t)b * PRE + i];
        v.x = fminf(fmaxf(bx.x, 0.f), 1.f);
        v.y = fminf(fmaxf(bx.y, 0.f), 1.f);
        v.z = fminf(fmaxf(bx.z, 0.f), 1.f);
        v.w = fminf(fmaxf(bx.w, 0.f), 1.f);
        sc = sscores[(size_t)b * PRE + i];
    }
    ((float4*)out)[t] = v;                 // roi_bboxes: first B*POST*4 floats
    out[(size_t)BATCH * POST * 4 + t] = sc; // roi_scores
}

// ---------------- host ----------------
extern "C" void kernel_launch(void* const* d_in, const int* in_sizes, int n_in,
                              void* d_out, int out_size, void* d_ws, size_t ws_size,
                              hipStream_t stream)
{
    const float* deltas  = (const float*)d_in[0];
    const float* probs   = (const float*)d_in[1];
    const float* anchors = (const float*)d_in[2];
    float* out = (float*)d_out;

    char* ws = (char*)d_ws;
    size_t off = 0;
    auto alloc = [&](size_t bytes) {
        size_t o = off;
        off = (off + bytes + 255) & ~(size_t)255;
        return o;
    };
    float4* boxes            = (float4*)(ws + alloc((size_t)BATCH * N_ANC * 16));
    unsigned long long* keys = (unsigned long long*)(ws + alloc((size_t)BATCH * SORT_N * 8));
    float4* sboxes           = (float4*)(ws + alloc((size_t)BATCH * PRE * 16));
    float* sscores           = (float*)(ws + alloc((size_t)BATCH * PRE * 4));
    unsigned int* mask       = (unsigned int*)(ws + alloc((size_t)BATCH * MROWS * ROWW * 4));
    int* oidx                = (int*)(ws + alloc((size_t)BATCH * POST * 4));
    int* ocnt                = (int*)(ws + alloc((size_t)BATCH * 4));

    k_decode<<<(BATCH * SORT_N + 255) / 256, 256, 0, stream>>>(deltas, probs, anchors, boxes, keys);
    k_sort<<<BATCH, 1024, 0, stream>>>(keys);
    k_gather<<<(BATCH * PRE + 255) / 256, 256, 0, stream>>>(keys, boxes, probs, sboxes, sscores);
    k_iou<<<dim3((PRE + 255) / 256, BATCH), 256, 0, stream>>>(sboxes, mask);
    k_scan<<<BATCH, 64, 0, stream>>>(mask, oidx, ocnt);
    k_out<<<(BATCH * POST + 255) / 256, 256, 0, stream>>>(sboxes, sscores, oidx, ocnt, out);
}

// Round 3
// 837.025 us; speedup vs baseline: 1.7797x; 1.7797x over previous
//
#include <hip/hip_runtime.h>
#include <hip/hip_bf16.h>

#define BATCH   16
#define N_ANC   8649      // 31*31*9
#define SORT_N  16384     // padded pow2
#define PRE     6000
#define POST    1500
#define ROWW    188       // u32 words per mask row (6016 bits)
#define MROWS   6016      // rows incl. pad (scan predicate stops loads at >=6016)
#define PFD     32        // scan prefetch depth (rows ahead)
#define TI      256
#define TJ      256

// ---------------- Kernel 1: decode boxes + build sort keys ----------------
__global__ __launch_bounds__(256) void k_decode(
    const float* __restrict__ deltas, const float* __restrict__ probs,
    const float* __restrict__ anchors, float4* __restrict__ boxes,
    unsigned long long* __restrict__ keys)
{
    int t = blockIdx.x * 256 + threadIdx.x;
    if (t >= BATCH * SORT_N) return;
    int b = t / SORT_N;
    int n = t - b * SORT_N;
    if (n >= N_ANC) { keys[t] = ~0ULL; return; }

    float s = probs[(size_t)b * N_ANC + n];
    unsigned int bits = __float_as_uint(s);
    unsigned int u = bits ^ ((bits & 0x80000000u) ? 0xFFFFFFFFu : 0x80000000u);
    keys[(size_t)b * SORT_N + n] = ((unsigned long long)(~u) << 32) | (unsigned int)n;

    float4 a = ((const float4*)anchors)[n];
    float4 d = ((const float4*)deltas)[(size_t)b * N_ANC + n];
    float dy = d.x * 0.1f, dx = d.y * 0.1f, dh = d.z * 0.2f, dw = d.w * 0.2f;
    float ah = a.z - a.x, aw = a.w - a.y;
    float cy = a.x + 0.5f * ah, cx = a.y + 0.5f * aw;
    float bh = expf(dh) * ah, bw = expf(dw) * aw;
    float bcy = dy * ah + cy, bcx = dx * aw + cx;
    float y1 = bcy - 0.5f * bh, x1 = bcx - 0.5f * bw;
    boxes[(size_t)b * N_ANC + n] = make_float4(y1, x1, y1 + bh, x1 + bw);
}

// ---------------- Kernel 2: per-batch bitonic sort of 16384 keys ----------------
__global__ __launch_bounds__(1024) void k_sort(unsigned long long* __restrict__ keys)
{
    __shared__ unsigned long long sb[8192];   // 64 KB
    int b = blockIdx.x;
    unsigned long long* kb = keys + (size_t)b * SORT_N;

    for (int c = 0; c < 2; c++) {
        unsigned long long* g = kb + c * 8192;
        for (int t = threadIdx.x; t < 8192; t += 1024) sb[t] = g[t];
        __syncthreads();
        for (int k = 2; k <= 8192; k <<= 1) {
            for (int j = k >> 1; j >= 1; j >>= 1) {
                for (int p = threadIdx.x; p < 4096; p += 1024) {
                    int i  = ((p & ~(j - 1)) << 1) | (p & (j - 1));
                    int gi = (c << 13) | i;
                    bool asc = ((gi & k) == 0);
                    unsigned long long a = sb[i], b2 = sb[i | j];
                    bool sw = asc ? (a > b2) : (a < b2);
                    if (sw) { sb[i] = b2; sb[i | j] = a; }
                }
                __syncthreads();
            }
        }
        for (int t = threadIdx.x; t < 8192; t += 1024) g[t] = sb[t];
        __syncthreads();
    }

    for (int p = threadIdx.x; p < 8192; p += 1024) {
        unsigned long long a = kb[p], b2 = kb[p + 8192];
        if (a > b2) { kb[p] = b2; kb[p + 8192] = a; }
    }
    __syncthreads();

    for (int t = threadIdx.x; t < 8192; t += 1024) sb[t] = kb[t];
    __syncthreads();
    for (int j = 4096; j >= 1; j >>= 1) {
        for (int p = threadIdx.x; p < 4096; p += 1024) {
            int i = ((p & ~(j - 1)) << 1) | (p & (j - 1));
            unsigned long long a = sb[i], b2 = sb[i | j];
            if (a > b2) { sb[i] = b2; sb[i | j] = a; }
        }
        __syncthreads();
    }
    for (int t = threadIdx.x; t < 6016; t += 1024) kb[t] = sb[t];
}

// ---------------- Kernel 3: gather sorted boxes/scores ----------------
__global__ __launch_bounds__(256) void k_gather(
    const unsigned long long* __restrict__ keys, const float4* __restrict__ boxes,
    const float* __restrict__ probs,
    float4* __restrict__ sboxes, float* __restrict__ sscores)
{
    int t = blockIdx.x * 256 + threadIdx.x;
    if (t >= BATCH * PRE) return;
    int b = t / PRE;
    int r = t - b * PRE;
    unsigned long long k = keys[(size_t)b * SORT_N + r];
    int idx = (int)(k & 0xFFFFFFFFu);
    sboxes[(size_t)b * PRE + r]  = boxes[(size_t)b * N_ANC + idx];
    sscores[(size_t)b * PRE + r] = probs[(size_t)b * N_ANC + idx];
}

// ---------------- Kernel 4: IoU bit-matrix, 256x256 tiles, upper triangle ----------------
__global__ __launch_bounds__(256) void k_iou(
    const float4* __restrict__ sboxes, unsigned int* __restrict__ mask)
{
    int it = blockIdx.x;   // row tile 0..23
    int jt = blockIdx.y;   // col tile 0..23
    int b  = blockIdx.z;
    if (jt < it) return;   // lower-triangle tiles never consumed by scan

    __shared__ float4 jb[TJ];
    __shared__ float  ja[TJ];
    int t = threadIdx.x;
    int j = jt * TJ + t;
    float4 bj = (j < PRE) ? sboxes[(size_t)b * PRE + j]
                          : make_float4(-2e6f, -2e6f, -1.5e6f, -1.5e6f); // far dummy, area>0
    jb[t] = bj;
    ja[t] = (bj.z - bj.x) * (bj.w - bj.y);
    __syncthreads();

    int i = it * TI + t;
    if (i >= PRE) return;
    float4 bi = sboxes[(size_t)b * PRE + i];
    float areai = (bi.z - bi.x) * (bi.w - bi.y);

    unsigned int w[8];
    if (jt > it) {
        // interior tile: every j > i, no per-element checks
        for (int wq = 0; wq < 8; wq++) {
            unsigned int bits = 0u;
            #pragma unroll
            for (int jj = 0; jj < 32; jj++) {
                int lj = wq * 32 + jj;
                float4 bx = jb[lj];
                float ih = fmaxf(fminf(bi.z, bx.z) - fmaxf(bi.x, bx.x), 0.0f);
                float iw = fmaxf(fminf(bi.w, bx.w) - fmaxf(bi.y, bx.y), 0.0f);
                float inter = ih * iw;
                float iou = inter / (areai + ja[lj] - inter + 1e-8f);
                if (iou > 0.7f) bits |= (1u << jj);
            }
            w[wq] = bits;
        }
    } else {
        // diagonal tile: predicate on j > i
        for (int wq = 0; wq < 8; wq++) {
            int jbase = jt * TJ + wq * 32;
            unsigned int bits = 0u;
            if (jbase + 31 > i) {
                #pragma unroll
                for (int jj = 0; jj < 32; jj++) {
                    int lj = wq * 32 + jj;
                    float4 bx = jb[lj];
                    float ih = fmaxf(fminf(bi.z, bx.z) - fmaxf(bi.x, bx.x), 0.0f);
                    float iw = fmaxf(fminf(bi.w, bx.w) - fmaxf(bi.y, bx.y), 0.0f);
                    float inter = ih * iw;
                    float iou = inter / (areai + ja[lj] - inter + 1e-8f);
                    if (iou > 0.7f && (jbase + jj) > i) bits |= (1u << jj);
                }
            }
            w[wq] = bits;
        }
    }

    unsigned int* row = mask + ((size_t)b * MROWS + i) * ROWW + jt * 8;
    ((uint4*)row)[0] = make_uint4(w[0], w[1], w[2], w[3]);
    if (jt < 23) ((uint4*)row)[1] = make_uint4(w[4], w[5], w[6], w[7]);
}

// ---------------- Kernel 5: sequential suppression scan (1 wave / batch) ----------------
__device__ __forceinline__ unsigned int word_bcast(uint4 st, int i)
{
    int w = i >> 5;                       // wave-uniform
    unsigned int t = (w & 2) ? ((w & 1) ? st.w : st.z)
                             : ((w & 1) ? st.y : st.x);
    return __shfl(t, w >> 2);
}

__global__ __launch_bounds__(64) void k_scan(
    const unsigned int* __restrict__ mask, int* __restrict__ out_idx,
    int* __restrict__ out_cnt)
{
    int b = blockIdx.x;
    int lane = threadIdx.x;
    const unsigned int* mb = mask + (size_t)b * MROWS * ROWW;
    bool lact = (lane < 47);              // lane l holds words 4l..4l+3

    uint4 st = make_uint4(0, 0, 0, 0);    // suppressed-state bits
    uint4 ring[PFD];

    #pragma unroll
    for (int d = 0; d < PFD; d++) {
        int r = d;
        int w0 = r >> 5;
        uint4 v = make_uint4(0, 0, 0, 0);
        if (lact && 4 * lane + 3 >= w0)
            v = *(const uint4*)(mb + (size_t)r * ROWW + 4 * lane);
        ring[d] = v;
    }

    int cnt = 0;
    int* oi = out_idx + b * POST;
    unsigned int cw = 0;
    for (int base = 0; base < PRE; base += PFD) {
        #pragma unroll
        for (int d = 0; d < PFD; d++) {
            int i = base + d;
            if ((i & 31) == 0) cw = word_bcast(st, i);  // compile-time: only d==0
            bool sup = (cw >> (i & 31)) & 1u;
            if (!sup && cnt < POST) {                   // wave-uniform branch
                if (lane == 0) oi[cnt] = i;
                cnt++;
                st.x |= ring[d].x; st.y |= ring[d].y;
                st.z |= ring[d].z; st.w |= ring[d].w;
                cw = word_bcast(st, i);
            }
            int r = i + PFD;
            int w0 = r >> 5;                            // >=188 for r>=6016 -> no load
            uint4 v = make_uint4(0, 0, 0, 0);
            if (lact && 4 * lane + 3 >= w0)
                v = *(const uint4*)(mb + (size_t)r * ROWW + 4 * lane);
            ring[d] = v;
        }
        if (cnt >= POST) break;
    }
    if (lane == 0) out_cnt[b] = cnt;
}

// ---------------- Kernel 6: compact + clip output ----------------
__global__ __launch_bounds__(256) void k_out(
    const float4* __restrict__ sboxes, const float* __restrict__ sscores,
    const int* __restrict__ out_idx, const int* __restrict__ out_cnt,
    float* __restrict__ out)
{
    int t = blockIdx.x * 256 + threadIdx.x;
    if (t >= BATCH * POST) return;
    int b = t / POST;
    int r = t - b * POST;
    float4 v = make_float4(0, 0, 0, 0);
    float sc = 0.f;
    if (r < out_cnt[b]) {
        int i = out_idx[b * POST + r];
        float4 bx = sboxes[(size_t)b * PRE + i];
        v.x = fminf(fmaxf(bx.x, 0.f), 1.f);
        v.y = fminf(fmaxf(bx.y, 0.f), 1.f);
        v.z = fminf(fmaxf(bx.z, 0.f), 1.f);
        v.w = fminf(fmaxf(bx.w, 0.f), 1.f);
        sc = sscores[(size_t)b * PRE + i];
    }
    ((float4*)out)[t] = v;                  // roi_bboxes
    out[(size_t)BATCH * POST * 4 + t] = sc; // roi_scores
}

// ---------------- host ----------------
extern "C" void kernel_launch(void* const* d_in, const int* in_sizes, int n_in,
                              void* d_out, int out_size, void* d_ws, size_t ws_size,
                              hipStream_t stream)
{
    const float* deltas  = (const float*)d_in[0];
    const float* probs   = (const float*)d_in[1];
    const float* anchors = (const float*)d_in[2];
    float* out = (float*)d_out;

    char* ws = (char*)d_ws;
    size_t off = 0;
    auto alloc = [&](size_t bytes) {
        size_t o = off;
        off = (off + bytes + 255) & ~(size_t)255;
        return o;
    };
    float4* boxes            = (float4*)(ws + alloc((size_t)BATCH * N_ANC * 16));
    unsigned long long* keys = (unsigned long long*)(ws + alloc((size_t)BATCH * SORT_N * 8));
    float4* sboxes           = (float4*)(ws + alloc((size_t)BATCH * PRE * 16));
    float* sscores           = (float*)(ws + alloc((size_t)BATCH * PRE * 4));
    unsigned int* mask       = (unsigned int*)(ws + alloc((size_t)BATCH * MROWS * ROWW * 4));
    int* oidx                = (int*)(ws + alloc((size_t)BATCH * POST * 4));
    int* ocnt                = (int*)(ws + alloc((size_t)BATCH * 4));

    k_decode<<<(BATCH * SORT_N + 255) / 256, 256, 0, stream>>>(deltas, probs, anchors, boxes, keys);
    k_sort<<<BATCH, 1024, 0, stream>>>(keys);
    k_gather<<<(BATCH * PRE + 255) / 256, 256, 0, stream>>>(keys, boxes, probs, sboxes, sscores);
    k_iou<<<dim3(24, 24, BATCH), 256, 0, stream>>>(sboxes, mask);
    k_scan<<<BATCH, 64, 0, stream>>>(mask, oidx, ocnt);
    k_out<<<(BATCH * POST + 255) / 256, 256, 0, stream>>>(sboxes, sscores, oidx, ocnt, out);
}